// Round 1
// baseline (1301.254 us; speedup 1.0000x reference)
//
#include <hip/hip_runtime.h>

// Problem: out[b][s][e] = sum_v inputs[b][v][s] * emb[v][e]
// B=128, V=2048, S=1024, E=64, fp32 in/out.
// Strategy: per-batch GEMM (M=S, N=E, K=V) with bf16 MFMA, fp32 accumulate.
// Memory-bound: 1.07 GB input stream is the roofline (~176 us at 6.3 TB/s).

typedef __attribute__((ext_vector_type(8))) short short8;   // 8 bf16 = 4 VGPRs (MFMA A/B frag)
typedef __attribute__((ext_vector_type(4))) float float4v;  // MFMA C/D frag

constexpr int Bc = 128, Vc = 2048, Sc = 1024, Ec = 64;
constexpr int BM = 128, BK = 32;   // block tile: 128(M) x 64(N=all of E) x 32(K)

// RNE float->bf16 (matches hardware rounding closely enough; NaN not expected here)
__device__ __forceinline__ short f2bf(float f) {
    union { float f; unsigned u; } x; x.f = f;
    unsigned u = x.u;
    u += 0x7fffu + ((u >> 16) & 1u);
    return (short)(u >> 16);
}

__global__ __launch_bounds__(256, 4)
void emb_mm(const float* __restrict__ A, const float* __restrict__ Emb,
            float* __restrict__ Out)
{
    // k-octet LDS layout: [kc][row][8 consecutive k] so fragment reads are ds_read_b128
    __shared__ short As[4][BM][8];   // 8 KB  (A tile, bf16)
    __shared__ short Bs[4][Ec][8];   // 4 KB  (Emb tile, bf16)

    const int tid  = threadIdx.x;
    const int lane = tid & 63;
    const int wave = tid >> 6;
    const int ml   = lane & 15;   // m (A) / n (B) / col (C) within 16-tile
    const int quad = lane >> 4;   // k-octet selector for A/B frags; row group for C

    const int blk = blockIdx.x;
    const int b   = blk >> 3;          // batch
    const int s0  = (blk & 7) * BM;    // M offset

    const float* Ab = A + (size_t)b * Vc * Sc + s0;

    // A staging: thread covers 2 (kc,m) pairs; 8 strided-coalesced dword loads each
    const int am  = tid & 127;         // m within tile (lanes consecutive -> coalesced)
    const int akc = tid >> 7;          // 0..1 (second pair is akc+2)
    // B staging: thread covers 1 (kc,n) pair
    const int bn  = tid & 63;
    const int bkc = tid >> 6;          // 0..3

    float4v acc[2][4];
    #pragma unroll
    for (int i = 0; i < 2; ++i)
        #pragma unroll
        for (int j = 0; j < 4; ++j)
            acc[i][j] = (float4v)0.f;

    for (int kt = 0; kt < Vc; kt += BK) {
        // ---- global loads (fp32), coalesced 256B runs along s / e ----
        float a0[8], a1[8], bb[8];
        const float* pA0 = Ab + (size_t)(kt + akc * 8) * Sc + am;
        const float* pA1 = pA0 + (size_t)16 * Sc;
        const float* pB  = Emb + (size_t)(kt + bkc * 8) * Ec + bn;
        #pragma unroll
        for (int j = 0; j < 8; ++j) {
            a0[j] = pA0[(size_t)j * Sc];
            a1[j] = pA1[(size_t)j * Sc];
            bb[j] = pB[(size_t)j * Ec];
        }
        // ---- convert to bf16, pack to 16B ----
        short8 pa0, pa1, pb;
        #pragma unroll
        for (int j = 0; j < 8; ++j) {
            pa0[j] = f2bf(a0[j]);
            pa1[j] = f2bf(a1[j]);
            pb[j]  = f2bf(bb[j]);
        }

        __syncthreads();   // previous iteration's frag reads done before overwrite
        *(short8*)&As[akc][am][0]     = pa0;
        *(short8*)&As[akc + 2][am][0] = pa1;
        *(short8*)&Bs[bkc][bn][0]     = pb;
        __syncthreads();   // staged data visible

        // ---- fragments + MFMA: wave owns M rows [wave*32, wave*32+32), all 64 N ----
        short8 af[2], bf[4];
        const int mbase = wave * 32 + ml;
        af[0] = *(const short8*)&As[quad][mbase][0];
        af[1] = *(const short8*)&As[quad][mbase + 16][0];
        #pragma unroll
        for (int nt = 0; nt < 4; ++nt)
            bf[nt] = *(const short8*)&Bs[quad][nt * 16 + ml][0];

        #pragma unroll
        for (int mt = 0; mt < 2; ++mt)
            #pragma unroll
            for (int nt = 0; nt < 4; ++nt)
                acc[mt][nt] = __builtin_amdgcn_mfma_f32_16x16x32_bf16(
                    af[mt], bf[nt], acc[mt][nt], 0, 0, 0);
    }

    // ---- epilogue: C/D layout col=lane&15, row=quad*4+reg (verified m89/m91) ----
    float* Ob = Out + ((size_t)b * Sc + s0 + wave * 32) * Ec;
    #pragma unroll
    for (int mt = 0; mt < 2; ++mt)
        #pragma unroll
        for (int nt = 0; nt < 4; ++nt)
            #pragma unroll
            for (int r = 0; r < 4; ++r) {
                const int row = mt * 16 + quad * 4 + r;
                const int col = nt * 16 + ml;
                Ob[row * Ec + col] = acc[mt][nt][r];
            }
}

extern "C" void kernel_launch(void* const* d_in, const int* in_sizes, int n_in,
                              void* d_out, int out_size, void* d_ws, size_t ws_size,
                              hipStream_t stream) {
    const float* A   = (const float*)d_in[0];   // inputs [B,V,S]
    const float* Emb = (const float*)d_in[1];   // embedding [V,E]
    float* Out       = (float*)d_out;           // [B,S,E]
    (void)in_sizes; (void)n_in; (void)out_size; (void)d_ws; (void)ws_size;
    emb_mm<<<dim3((Bc * Sc) / BM), dim3(256), 0, stream>>>(A, Emb, Out);
}